// Round 1
// baseline (195.027 us; speedup 1.0000x reference)
//
#include <hip/hip_runtime.h>

// Problem constants (from reference): WINDOW_SIZE=2, resolution/min-range for
// cartesian->radar conversion. Done in f64 for free (memory-bound kernel).
#define RES  0.2592
#define MINR 82.8144   // (640/2 - 0.5) * 0.2592

// ---------------------------------------------------------------------------
// Kernel 1: per-batch weighted reduction of 9 moments over N points.
//   acc = [ W, Sx, Sy, Tx, Ty, Mxx, Mxy, Myx, Myy ]
// where s/t are radar-frame src/tgt coords, M_ij = sum w * t_i * s_j.
// Grid: (bpb, B). Each block strides over the batch's point-pairs.
// f64 accumulation (centroid-subtraction cancellation at N=100k needs it).
// ---------------------------------------------------------------------------
__global__ __launch_bounds__(256) void svd_reduce(
    const float4* __restrict__ kp,   // keypoint_coords viewed as pairs-of-points
    const float4* __restrict__ tg,   // tgt_coords viewed as pairs-of-points
    const float2* __restrict__ wt,   // weights viewed as pairs
    double* __restrict__ ws,         // [B][9] accumulators (pre-zeroed)
    int npairs, int bpb)
{
    const int batch = blockIdx.y;
    // src takes every WINDOW_SIZE=2-th row of keypoint_coords -> row 2*batch
    const float4* __restrict__ src = kp + (size_t)(2 * batch) * npairs;
    const float4* __restrict__ tgt = tg + (size_t)batch * npairs;
    const float2* __restrict__ wp  = wt + (size_t)batch * npairs;

    double aW = 0, aSx = 0, aSy = 0, aTx = 0, aTy = 0;
    double aXX = 0, aXY = 0, aYX = 0, aYY = 0;

    for (int i = blockIdx.x * 256 + threadIdx.x; i < npairs; i += bpb * 256) {
        float4 s4 = src[i];
        float4 t4 = tgt[i];
        float2 w2 = wp[i];

        // point 0 of the pair
        {
            double w  = (double)w2.x;
            double sx = MINR - RES * (double)s4.y;
            double sy = RES * (double)s4.x - MINR;
            double tx = MINR - RES * (double)t4.y;
            double ty = RES * (double)t4.x - MINR;
            double wtx = w * tx, wty = w * ty;
            aW  += w;
            aSx += w * sx;   aSy += w * sy;
            aTx += wtx;      aTy += wty;
            aXX += wtx * sx; aXY += wtx * sy;
            aYX += wty * sx; aYY += wty * sy;
        }
        // point 1 of the pair
        {
            double w  = (double)w2.y;
            double sx = MINR - RES * (double)s4.w;
            double sy = RES * (double)s4.z - MINR;
            double tx = MINR - RES * (double)t4.w;
            double ty = RES * (double)t4.z - MINR;
            double wtx = w * tx, wty = w * ty;
            aW  += w;
            aSx += w * sx;   aSy += w * sy;
            aTx += wtx;      aTy += wty;
            aXX += wtx * sx; aXY += wtx * sy;
            aYX += wty * sx; aYY += wty * sy;
        }
    }

    double acc[9] = {aW, aSx, aSy, aTx, aTy, aXX, aXY, aYX, aYY};

    // 64-lane wave reduction (wavefront = 64 on CDNA)
    #pragma unroll
    for (int k = 0; k < 9; k++) {
        #pragma unroll
        for (int off = 32; off > 0; off >>= 1)
            acc[k] += __shfl_down(acc[k], off, 64);
    }

    __shared__ double sred[4][9];
    const int lane = threadIdx.x & 63;
    const int wid  = threadIdx.x >> 6;
    if (lane == 0) {
        #pragma unroll
        for (int k = 0; k < 9; k++) sred[wid][k] = acc[k];
    }
    __syncthreads();
    if (threadIdx.x < 9) {
        double v = sred[0][threadIdx.x] + sred[1][threadIdx.x] +
                   sred[2][threadIdx.x] + sred[3][threadIdx.x];
        unsafeAtomicAdd(&ws[(size_t)batch * 9 + threadIdx.x], v);  // HW f64 atomic
    }
}

// ---------------------------------------------------------------------------
// Kernel 2: closed-form finalize. One thread per batch.
// Wc's 3rd row/col are exactly zero, so the 3x3 SVD collapses:
//   R2 = polar factor U2*V2h of the 2x2 covariance A; R[2][2] = sign(det A).
// det A >= 0  -> closest rotation   [[a+d, b-c],[c-b, a+d]]/h1
// det A <  0  -> closest reflection [[a-d, b+c],[b+c, d-a]]/h2
// (det A = (h1^2 - h2^2)/4, so branch on h1 >= h2.)
// ---------------------------------------------------------------------------
__global__ void svd_finalize(const double* __restrict__ ws,
                             float* __restrict__ out, int B)
{
    int b = blockIdx.x * blockDim.x + threadIdx.x;
    if (b >= B) return;
    const double* s = ws + (size_t)b * 9;
    double W  = s[0];
    double Sx = s[1], Sy = s[2], Tx = s[3], Ty = s[4];
    double Mxx = s[5], Mxy = s[6], Myx = s[7], Myy = s[8];

    double invW = 1.0 / W;
    // A[i][j] = (M_ij - T_i * S_j / W) / W   (i: tgt row, j: src col)
    double a  = (Mxx - Tx * Sx * invW) * invW;
    double bb = (Mxy - Tx * Sy * invW) * invW;
    double c  = (Myx - Ty * Sx * invW) * invW;
    double d  = (Myy - Ty * Sy * invW) * invW;

    double h1 = sqrt((a + d) * (a + d) + (bb - c) * (bb - c));
    double h2 = sqrt((a - d) * (a - d) + (bb + c) * (bb + c));

    double q00, q01, q10, q11, sgn;
    if (h1 >= h2) {            // det A >= 0 : rotation
        double inv = 1.0 / h1;
        q00 = (a + d) * inv;  q01 = (bb - c) * inv;
        q10 = (c - bb) * inv; q11 = (a + d) * inv;
        sgn = 1.0;
    } else {                   // det A < 0 : reflection (still exactly U2*V2h)
        double inv = 1.0 / h2;
        q00 = (a - d) * inv;  q01 = (bb + c) * inv;
        q10 = (bb + c) * inv; q11 = (d - a) * inv;
        sgn = -1.0;
    }

    double sx = Sx * invW, sy = Sy * invW;
    double tx = Tx * invW, ty = Ty * invW;

    // t1 = src_centroid - R^T * tgt_centroid
    double t1x = sx - (q00 * tx + q10 * ty);
    double t1y = sy - (q01 * tx + q11 * ty);
    // t_out = -R * t1
    double ox = -(q00 * t1x + q01 * t1y);
    double oy = -(q10 * t1x + q11 * t1y);

    // Output 0: R_tgt_src.transpose(0,2,1), row-major per batch.
    // R = [[q00,q01,0],[q10,q11,0],[0,0,sgn]]  ->  R^T rows:
    float* R = out + (size_t)b * 9;
    R[0] = (float)q00; R[1] = (float)q10; R[2] = 0.0f;
    R[3] = (float)q01; R[4] = (float)q11; R[5] = 0.0f;
    R[6] = 0.0f;       R[7] = 0.0f;       R[8] = (float)sgn;

    // Output 1: t_src_tgt_intgt, (B,3,1) appended after the B*9 rotations.
    float* T = out + (size_t)B * 9 + (size_t)b * 3;
    T[0] = (float)ox; T[1] = (float)oy; T[2] = 0.0f;
}

extern "C" void kernel_launch(void* const* d_in, const int* in_sizes, int n_in,
                              void* d_out, int out_size, void* d_ws, size_t ws_size,
                              hipStream_t stream) {
    const float* kp = (const float*)d_in[0];  // (B*2, N, 2) f32
    const float* tg = (const float*)d_in[1];  // (B,   N, 2) f32
    const float* wt = (const float*)d_in[2];  // (B, 1, N)   f32
    float* out = (float*)d_out;               // B*9 + B*3 f32

    const int B = out_size / 12;              // 64
    const int N = in_sizes[2] / B;            // 100000
    const int npairs = N / 2;                 // N is even
    const int BPB = 32;                       // blocks per batch -> 2048 blocks

    // zero the f64 accumulators (d_ws is poisoned 0xAA before every launch)
    hipMemsetAsync(d_ws, 0, (size_t)B * 9 * sizeof(double), stream);

    dim3 grid(BPB, B);
    svd_reduce<<<grid, 256, 0, stream>>>(
        (const float4*)kp, (const float4*)tg, (const float2*)wt,
        (double*)d_ws, npairs, BPB);

    svd_finalize<<<(B + 63) / 64, 64, 0, stream>>>((const double*)d_ws, out, B);
}